// Round 4
// baseline (67.662 us; speedup 1.0000x reference)
//
#include <hip/hip_runtime.h>

#define HDIM 1024
#define NW 18            // 6 gate rows + 12 expert rows (e*2+l)
#define NTHREADS 256
#define RPT 4                // rows per lane
#define ROWS_PER_BLOCK 128   // 4 waves x 8 clusters x RPT

typedef float f32x4 __attribute__((ext_vector_type(4)));

// Structure (R4):
//  - Weights (72 KB) staged once into LDS, interleaved [slot s=0..255][w=0..17] f32x4:
//    per j-iteration ONE lane address + 18 ds_read_b128 (8-way broadcast across
//    clusters, 2-way bank aliasing across c -> free).
//  - Wave = 8 clusters x 8 lanes; cluster reads a full 128B line per row per j.
//  - RPT=4 rows/lane -> acc[4][18]=72 VGPR, ~120 total -> 2 waves/SIMD
//    (2 blocks/CU, 144KB LDS). TLP covers vmcnt/lgkmcnt stalls that were fully
//    exposed at 1 wave/SIMD in R3.
//  - x stream: nontemporal (single-use), 2-buffer prefetch distance 1.
__global__ __launch_bounds__(NTHREADS, 2)
void hardmoe_kernel(const float* __restrict__ cls,
                    const float* __restrict__ gate_w,
                    const float* __restrict__ gate_b,
                    const float* __restrict__ expert_w,
                    const float* __restrict__ expert_b,
                    float* __restrict__ out, int B)
{
    __shared__ f32x4 Wl[256 * NW];   // 72 KB

    const int t = threadIdx.x;

    // ---- Stage weights: thread t owns f4-slot s=t for all 18 w (coalesced per w) ----
    {
        const int s = t;
#pragma unroll
        for (int w = 0; w < NW; ++w) {
            const float* src = (w < 6) ? (gate_w + (size_t)w * HDIM)
                                       : (expert_w + (size_t)(w - 6) * HDIM);
            Wl[s * NW + w] = *(reinterpret_cast<const f32x4*>(src) + s);
        }
    }

    // ---- Biases (uniform -> scalar) ----
    float gb[6], eb[12];
#pragma unroll
    for (int e = 0; e < 6; ++e) gb[e] = gate_b[e];
#pragma unroll
    for (int k = 0; k < 12; ++k) eb[k] = expert_b[k];

    __syncthreads();

    const int wv = t >> 6;       // wave 0..3
    const int l  = t & 63;
    const int s8 = l >> 3;       // cluster 0..7
    const int c  = l & 7;        // col sublane 0..7

    const int wavebase = blockIdx.x * ROWS_PER_BLOCK + wv * (8 * RPT);

    const float* px[RPT];
    int rows[RPT];
#pragma unroll
    for (int k = 0; k < RPT; ++k) {
        int r = wavebase + k * 8 + s8;
        rows[k] = r;
        int rc = r < B ? r : B - 1;
        px[k] = cls + (size_t)rc * HDIM + c * 4;
    }

    float acc[RPT][NW];
#pragma unroll
    for (int k = 0; k < RPT; ++k)
#pragma unroll
        for (int w = 0; w < NW; ++w) acc[k][w] = 0.f;

    f32x4 xA[RPT], xB[RPT];
#pragma unroll
    for (int k = 0; k < RPT; ++k)
        xA[k] = __builtin_nontemporal_load(reinterpret_cast<const f32x4*>(px[k]));

    for (int j = 0; j < 32; j += 2) {
        // prefetch j+1
#pragma unroll
        for (int k = 0; k < RPT; ++k)
            xB[k] = __builtin_nontemporal_load(
                reinterpret_cast<const f32x4*>(px[k] + (size_t)(j + 1) * 32));
        // compute j with xA
        {
            const f32x4* wp = &Wl[(j * 8 + c) * NW];
#pragma unroll
            for (int w = 0; w < NW; ++w) {
                f32x4 wf = wp[w];
#pragma unroll
                for (int k = 0; k < RPT; ++k) {
                    float a = acc[k][w];
                    a = fmaf(xA[k].x, wf.x, a);
                    a = fmaf(xA[k].y, wf.y, a);
                    a = fmaf(xA[k].z, wf.z, a);
                    a = fmaf(xA[k].w, wf.w, a);
                    acc[k][w] = a;
                }
            }
        }
        // prefetch j+2
        if (j + 2 < 32) {
#pragma unroll
            for (int k = 0; k < RPT; ++k)
                xA[k] = __builtin_nontemporal_load(
                    reinterpret_cast<const f32x4*>(px[k] + (size_t)(j + 2) * 32));
        }
        // compute j+1 with xB
        {
            const f32x4* wq = &Wl[((j + 1) * 8 + c) * NW];
#pragma unroll
            for (int w = 0; w < NW; ++w) {
                f32x4 wf = wq[w];
#pragma unroll
                for (int k = 0; k < RPT; ++k) {
                    float a = acc[k][w];
                    a = fmaf(xB[k].x, wf.x, a);
                    a = fmaf(xB[k].y, wf.y, a);
                    a = fmaf(xB[k].z, wf.z, a);
                    a = fmaf(xB[k].w, wf.w, a);
                    acc[k][w] = a;
                }
            }
        }
    }

    // ---- Reduce across the 8-lane cluster (c dimension): xor 1,2,4 ----
#pragma unroll
    for (int k = 0; k < RPT; ++k)
#pragma unroll
        for (int w = 0; w < NW; ++w) {
            float v = acc[k][w];
            v += __shfl_xor(v, 1);
            v += __shfl_xor(v, 2);
            v += __shfl_xor(v, 4);
            acc[k][w] = v;
        }

    // ---- Per row: gate argmax (strict >, first-max tiebreak) + expert select ----
#pragma unroll
    for (int k = 0; k < RPT; ++k) {
        float best = acc[k][0] + gb[0];
        int idx = 0;
#pragma unroll
        for (int e = 1; e < 6; ++e) {
            float v = acc[k][e] + gb[e];
            if (v > best) { best = v; idx = e; }
        }
        float o0 = 0.f, o1 = 0.f;
#pragma unroll
        for (int e = 0; e < 6; ++e) {
            bool m = (idx == e);
            o0 = m ? (acc[k][6 + 2 * e] + eb[2 * e])     : o0;
            o1 = m ? (acc[k][7 + 2 * e] + eb[2 * e + 1]) : o1;
        }
        if (c == 0 && rows[k] < B)
            *reinterpret_cast<float2*>(out + (size_t)rows[k] * 2) = make_float2(o0, o1);
    }
}

extern "C" void kernel_launch(void* const* d_in, const int* in_sizes, int n_in,
                              void* d_out, int out_size, void* d_ws, size_t ws_size,
                              hipStream_t stream) {
    const float* cls      = (const float*)d_in[0];
    const float* gate_w   = (const float*)d_in[1];
    const float* gate_b   = (const float*)d_in[2];
    const float* expert_w = (const float*)d_in[3];
    const float* expert_b = (const float*)d_in[4];
    float* out = (float*)d_out;

    const int B = in_sizes[0] / HDIM;
    const int grid = (B + ROWS_PER_BLOCK - 1) / ROWS_PER_BLOCK;

    hardmoe_kernel<<<grid, NTHREADS, 0, stream>>>(cls, gate_w, gate_b,
                                                  expert_w, expert_b, out, B);
}